// Round 30
// baseline (843.345 us; speedup 1.0000x reference)
//
#include <hip/hip_runtime.h>
#include <hip/hip_bf16.h>

typedef _Float16 f16;
typedef unsigned short u16;
typedef unsigned int   u32;
typedef __attribute__((ext_vector_type(8))) _Float16 f16x8;
typedef __attribute__((ext_vector_type(4))) float    f32x4;

__device__ __forceinline__ float h2fu(u16 u) { union { u16 s; f16 h; } t; t.s = u; return (float)t.h; }
__device__ __forceinline__ u16   f2h(float f) { union { u16 s; f16 h; } t; t.h = (f16)f; return t.s; }
__device__ __forceinline__ float geluf(float u) { return 0.5f*u*(1.0f + erff(u*0.70710678118654752f)); }
__device__ __forceinline__ float sigmf(float x) { return 1.0f/(1.0f + __expf(-x)); }
__device__ __forceinline__ float tanhfast(float x) { return 1.0f - 2.0f/(__expf(2.0f*x) + 1.0f); }

// async global->LDS DMA, 16 bytes/lane; lds base must be wave-uniform.
__device__ __forceinline__ void gload16(const void* gp, void* lp) {
  __builtin_amdgcn_global_load_lds(
      (const __attribute__((address_space(1))) u32*)gp,
      (__attribute__((address_space(3))) u32*)lp, 16, 0, 0);
}

// ---------------------------------------------------------------------------
// One-shot prep for gat<128>: W^T in f16 with the PAD BAKED IN (128 rows of
// 136, cols [128,136) zero).  Lives at W8+0 (feat region — dead after gat<64>).
// ---------------------------------------------------------------------------
__global__ __launch_bounds__(256) void k_prep_gat2(
    const float* __restrict__ g2w, u16* __restrict__ wt2p) {
  int i = blockIdx.x*256 + threadIdx.x;   // 68 blocks * 256 = 17408 exactly
  int c = i/136, k = i%136;
  wt2p[i] = (k < 128) ? f2h(g2w[k*128 + c]) : (u16)0;
}

// ---------------------------------------------------------------------------
// One-shot prep: f32->f16 row-major copies of the small-K GEMM weights so
// their B-staging becomes pure DMA (no per-K-step cvt chain).  Placed in
// [144,192) MiB — dead forever once dual2-1 retires g (launched after it).
//   o0 = l1f_wih [512][256]   o1 = l1b_wih [512][256]
//   o2 = mha_in_w [768][256]  o3 = mha_out_w [256][256]
// ---------------------------------------------------------------------------
__global__ __launch_bounds__(256) void k_prep_w(
    const float* __restrict__ w0, const float* __restrict__ w1,
    const float* __restrict__ w2, const float* __restrict__ w3,
    u16* __restrict__ o0, u16* __restrict__ o1,
    u16* __restrict__ o2, u16* __restrict__ o3) {
  int i = blockIdx.x*256 + threadIdx.x;
  int stride = gridDim.x*256;
  for (int j = i; j < 131072; j += stride) o0[j] = f2h(w0[j]);
  for (int j = i; j < 131072; j += stride) o1[j] = f2h(w1[j]);
  for (int j = i; j < 196608; j += stride) o2[j] = f2h(w2[j]);
  for (int j = i; j < 65536;  j += stride) o3[j] = f2h(w3[j]);
}

// ---------------------------------------------------------------------------
// Fused conv1(1->32,k7,p3)+bn+gelu -> conv2 via SPLIT-K im2col MFMA.
// (exact r24/r27-validated form: in-kernel W conversion)
// ---------------------------------------------------------------------------
__global__ __launch_bounds__(256) void k_conv(
    const float* __restrict__ x,
    const float* __restrict__ w1, const float* __restrict__ cb1v,
    const float* __restrict__ g1v, const float* __restrict__ be1v,
    const float* __restrict__ w2, const float* __restrict__ cb2v,
    const float* __restrict__ g2v, const float* __restrict__ be2v,
    f16* __restrict__ feat) {
  __shared__ float xs[262];
  __shared__ __align__(16) u16 xcol[128*104];   // per-half im2col [t2][icl*5+kk]
  __shared__ __align__(16) u16 wcol[64*184];    // [oc][ic*5+kk], stride 184
  __shared__ float w1l[224];
  __shared__ float cb1[32], sc1[32], sb1[32];
  __shared__ float cb2[64], sc2[64], sb2[64];
  int r = blockIdx.x, tid = threadIdx.x;
  int bb = r >> 4, n = r & 15;
  for (int i = tid; i < 262; i += 256) {
    int p = i - 3;
    xs[i] = (p >= 0 && p < 256) ? x[(size_t)r*256 + p] : 0.0f;
  }
  if (tid < 224) {
    w1l[tid] = w1[tid];
  } else {
    int oc = tid - 224;
    cb1[oc] = cb1v[oc];
    sc1[oc] = g1v[oc] * rsqrtf(1.0f + 1e-5f);
    sb1[oc] = be1v[oc];
  }
  for (int i = tid; i < 10240; i += 256) {
    int oc = i/160, c = i%160;
    wcol[oc*184 + c] = f2h(w2[i]);
  }
  for (int i = tid; i < 64*24; i += 256) {       // zero wcol cols [160,184)
    int oc = i/24, c = 160 + i%24;
    wcol[oc*184 + c] = 0;
  }
  if (tid < 64) {
    cb2[tid] = cb2v[tid];
    sc2[tid] = g2v[tid] * rsqrtf(1.0f + 1e-5f);
    sb2[tid] = be2v[tid];
  }
  // zero xcol K-pad cols [80,96) for all rows (persist across halves)
  for (int i = tid; i < 2048; i += 256) {
    int row = i >> 4, c = 80 + (i & 15);
    xcol[row*104 + c] = 0;
  }
  // zero boundary cells (never scatter-written): t2=0 kk in {0,1}; t2=127 kk=4
  if (tid < 48) {
    if (tid < 32) { int icl = tid >> 1, kk = tid & 1; xcol[icl*5 + kk] = 0; }
    else          { int icl = tid - 32; xcol[127*104 + icl*5 + 4] = 0; }
  }
  __syncthreads();                               // B1
  float xv[7];
  #pragma unroll
  for (int k = 0; k < 7; k++) xv[k] = xs[tid + k];
  int offs[3]; int noff = 0;
  #pragma unroll
  for (int j = 0; j < 3; j++) {
    int kk = (tid & 1) + 2*j;
    if (kk < 5) {
      int t2 = (tid + 2 - kk) >> 1;
      if (t2 >= 0 && t2 < 128) { offs[noff] = t2*104 + kk; noff++; }
    }
  }
  int wave = tid >> 6, lane = tid & 63;
  int lr = lane & 15, lg = lane >> 4;
  f32x4 acc[2][4];
  #pragma unroll
  for (int mi = 0; mi < 2; mi++)
    #pragma unroll
    for (int nt = 0; nt < 4; nt++)
      acc[mi][nt] = (f32x4){0.0f, 0.0f, 0.0f, 0.0f};
  #pragma unroll
  for (int h = 0; h < 2; h++) {
    for (int icl = 0; icl < 16; icl++) {
      int oc = h*16 + icl;
      float a = cb1[oc];
      #pragma unroll
      for (int k = 0; k < 7; k++) a += w1l[oc*7 + k]*xv[k];
      u16 hv = f2h(geluf(a*sc1[oc] + sb1[oc]));
      for (int i2 = 0; i2 < noff; i2++) xcol[offs[i2] + icl*5] = hv;
    }
    __syncthreads();                             // scatter done
    f16x8 af[2][3];
    #pragma unroll
    for (int mi = 0; mi < 2; mi++)
      #pragma unroll
      for (int kb = 0; kb < 3; kb++)
        af[mi][kb] = *(const f16x8*)&xcol[((wave*2 + mi)*16 + lr)*104 + kb*32 + lg*8];
    #pragma unroll
    for (int nt = 0; nt < 4; nt++) {
      f16x8 bf[3];
      #pragma unroll
      for (int kb = 0; kb < 3; kb++)
        bf[kb] = *(const f16x8*)&wcol[(nt*16 + lr)*184 + h*80 + kb*32 + lg*8];
      #pragma unroll
      for (int mi = 0; mi < 2; mi++)
        #pragma unroll
        for (int kb = 0; kb < 3; kb++)
          acc[mi][nt] = __builtin_amdgcn_mfma_f32_16x16x32_f16(af[mi][kb], bf[kb], acc[mi][nt], 0, 0, 0);
    }
    if (h == 0) __syncthreads();                 // MFMA reads done before half-1 scatter
  }
  #pragma unroll
  for (int nt = 0; nt < 4; nt++) {
    int oc = nt*16 + lr;
    float c2 = cb2[oc], s2 = sc2[oc], b2 = sb2[oc];
    #pragma unroll
    for (int mi = 0; mi < 2; mi++) {
      #pragma unroll
      for (int q = 0; q < 4; q++) {
        int t2 = (wave*2 + mi)*16 + lg*4 + q;
        float u = (acc[mi][nt][q] + c2)*s2 + b2;
        feat[(((size_t)bb*128 + t2)*16 + n)*64 + oc] = (f16)geluf(u);
      }
    }
  }
}

// ---------------------------------------------------------------------------
// GAT layer (+ReLU +LayerNorm), LDS-aliased, 3 barriers (r22/r24-validated).
// DW=false: W staged f32->f16 into LDS per block.
// DW=true : W staged via linear gload16 DMA from pre-padded f16 image. (r27)
// ---------------------------------------------------------------------------
template<int F, bool DW>
__global__ __launch_bounds__(512) void k_gat_mfma(
    const float* __restrict__ W, const f16* __restrict__ Wt,
    const f16* __restrict__ xin,
    const float* __restrict__ asrc, const float* __restrict__ adst,
    const float* __restrict__ gng, const float* __restrict__ gnb,
    f16* __restrict__ gout) {
  constexpr int XP = F + 8;
  constexpr int ASZ = (128*XP > 512*24) ? 128*XP : 512*24;   // xa | alx
  constexpr int BSZ = 128*144;                               // wt | hT
  __shared__ __align__(16) u16 regA[ASZ];
  __shared__ __align__(16) u16 regB[BSZ];
  __shared__ float esl[512], edl[512];
  __shared__ float wsv[128], wdv[128], gngl[128], gnbl[128];
  u16* xa  = regA;
  u16* alx = regA;
  u16* wt  = regB;
  u16* hT  = regB;
  int tid = threadIdx.x;
  size_t rowbase = (size_t)blockIdx.x*128;
  const u32* xg = (const u32*)(xin + rowbase*F);
  if constexpr (DW) {
    int wbase = tid & ~63;
    #pragma unroll
    for (int it = 0; it < 4; it++) {
      int cc = it*512 + tid;
      gload16((const u16*)Wt + cc*8, wt + (size_t)(it*512 + wbase)*8);
    }
    if (tid < 128)
      gload16((const u16*)Wt + (2048 + tid)*8, wt + (size_t)(2048 + wbase)*8);
  }
  for (int i = tid; i < 128*F/2; i += 512) {
    u32 v = xg[i];
    int r = (2*i)/F, k = (2*i)%F;
    *(u32*)&xa[r*XP + k] = v;
  }
  if constexpr (!DW) {
    for (int i = tid; i < F*128; i += 512) {
      int k = i >> 7, c = i & 127;
      wt[c*XP + k] = f2h(W[i]);
    }
  }
  if (tid < 128) {
    wsv[tid] = asrc[tid]; wdv[tid] = adst[tid];
    gngl[tid] = gng[tid]; gnbl[tid] = gnb[tid];
  }
  __syncthreads();                 // B1 (drains DMA vmcnt)
  int wave = tid >> 6, lane = tid & 63;
  int lr = lane & 15, lg = lane >> 4;
  int g = wave;
  f32x4 dacc[8];
  {
    f16x8 af[F/32];
    #pragma unroll
    for (int kb = 0; kb < F/32; kb++)
      af[kb] = *(const f16x8*)&xa[(g*16 + lr)*XP + kb*32 + lg*8];
    #pragma unroll
    for (int nt = 0; nt < 8; nt++) {
      f32x4 a = {0.0f, 0.0f, 0.0f, 0.0f};
      #pragma unroll
      for (int kb = 0; kb < F/32; kb++) {
        f16x8 bf = *(const f16x8*)&wt[(nt*16 + lr)*XP + kb*32 + lg*8];
        a = __builtin_amdgcn_mfma_f32_16x16x32_f16(af[kb], bf, a, 0, 0, 0);
      }
      dacc[nt] = a;
    }
  }
  #pragma unroll
  for (int q = 0; q < 4; q++) {
    #pragma unroll
    for (int hh = 0; hh < 4; hh++) {
      float es = dacc[2*hh][q]*wsv[hh*32 + lr] + dacc[2*hh+1][q]*wsv[hh*32 + 16 + lr];
      float ed = dacc[2*hh][q]*wdv[hh*32 + lr] + dacc[2*hh+1][q]*wdv[hh*32 + 16 + lr];
      es += __shfl_xor(es, 1); es += __shfl_xor(es, 2);
      es += __shfl_xor(es, 4); es += __shfl_xor(es, 8);
      ed += __shfl_xor(ed, 1); ed += __shfl_xor(ed, 2);
      ed += __shfl_xor(ed, 4); ed += __shfl_xor(ed, 8);
      if (lr == 0) {
        int nn = lg*4 + q;
        esl[g*64 + nn*4 + hh] = es;
        edl[g*64 + nn*4 + hh] = ed;
      }
    }
  }
  __syncthreads();                 // B2: all reads of xa (regA) / wt (regB) done
  #pragma unroll
  for (int nt = 0; nt < 8; nt++) {
    int col = nt*16 + lr;
    ushort4 hv;
    hv.x = f2h(dacc[nt][0]); hv.y = f2h(dacc[nt][1]);
    hv.z = f2h(dacc[nt][2]); hv.w = f2h(dacc[nt][3]);
    *(ushort4*)&hT[col*144 + g*16 + lg*4] = hv;
  }
  for (int z = lane; z < 256; z += 64) {
    int col = g*16 + (z >> 4);
    hT[col*144 + 128 + (z & 15)] = 0;
  }
  {
    int i = lr, hh = lg;
    float ei = esl[g*64 + i*4 + hh];
    float pv[16]; float mx = -1e30f;
    #pragma unroll
    for (int j = 0; j < 16; j++) {
      float e = ei + edl[g*64 + j*4 + hh];
      e = (e < 0.0f) ? 0.2f*e : e;
      pv[j] = e; mx = fmaxf(mx, e);
    }
    float sum = 0.0f;
    #pragma unroll
    for (int j = 0; j < 16; j++) { float pe = __expf(pv[j] - mx); pv[j] = pe; sum += pe; }
    float inv = 1.0f/sum;
    u16* ap = &alx[((g*4 + hh)*16 + i)*24];
    #pragma unroll
    for (int j = 0; j < 16; j++) ap[j] = f2h(pv[j]*inv);
  }
  __syncthreads();                 // B3: hT/alx fully written before PV reads
  f32x4 oacc[4][2];
  #pragma unroll
  for (int hh = 0; hh < 4; hh++) {
    f16x8 pa = {};
    if (lg < 2) pa = *(const f16x8*)&alx[((g*4 + hh)*16 + lr)*24 + lg*8];
    #pragma unroll
    for (int nh = 0; nh < 2; nh++) {
      f16x8 bv = *(const f16x8*)&hT[(hh*32 + nh*16 + lr)*144 + g*16 + lg*8];
      f32x4 z = {0.0f, 0.0f, 0.0f, 0.0f};
      oacc[hh][nh] = __builtin_amdgcn_mfma_f32_16x16x32_f16(pa, bv, z, 0, 0, 0);
    }
  }
  #pragma unroll
  for (int q = 0; q < 4; q++) {
    float v[8];
    float s = 0.0f, sq = 0.0f;
    #pragma unroll
    for (int hh = 0; hh < 4; hh++)
      #pragma unroll
      for (int nh = 0; nh < 2; nh++) {
        float t = fmaxf(oacc[hh][nh][q], 0.0f);
        v[hh*2 + nh] = t; s += t; sq += t*t;
      }
    s  += __shfl_xor(s, 1);  sq += __shfl_xor(sq, 1);
    s  += __shfl_xor(s, 2);  sq += __shfl_xor(sq, 2);
    s  += __shfl_xor(s, 4);  sq += __shfl_xor(sq, 4);
    s  += __shfl_xor(s, 8);  sq += __shfl_xor(sq, 8);
    float mean = s*(1.0f/128.0f);
    float var  = sq*(1.0f/128.0f) - mean*mean;
    float rstd = rsqrtf(var + 1e-5f);
    size_t row = rowbase + g*16 + lg*4 + q;
    u16* orow = (u16*)(gout + row*128);
    #pragma unroll
    for (int hh = 0; hh < 4; hh++)
      #pragma unroll
      for (int nh = 0; nh < 2; nh++) {
        int col = hh*32 + nh*16 + lr;
        orow[col] = f2h((v[hh*2 + nh] - mean)*rstd*gngl[col] + gnbl[col]);
      }
  }
}

// ---------------------------------------------------------------------------
// MFMA GEMM core (f16 W image, 128-m-tile) — BOTH sides staged via DMA
// (same validated index mapping as r20/r29; W pre-converted by k_prep_w).
// ---------------------------------------------------------------------------
__device__ __forceinline__ void gemm_body(
    const f16* __restrict__ A, const f16* __restrict__ Wh,
    const float* __restrict__ bias1, const float* __restrict__ bias2,
    f16* __restrict__ C, int M, int N, int K, int m0, int n0, u16* lds) {
  u16* As = lds;
  u16* Bs = lds + 128*64;
  int tid = threadIdx.x;
  int wave = tid >> 6, lane = tid & 63;
  int wm = wave >> 1, wn = wave & 1;
  int lr = lane & 15, lg = lane >> 4;
  int wbase = tid & ~63;
  f32x4 acc[4][4];
  #pragma unroll
  for (int mi = 0; mi < 4; mi++)
    #pragma unroll
    for (int ni = 0; ni < 4; ni++)
      acc[mi][ni] = (f32x4){0.0f, 0.0f, 0.0f, 0.0f};
  for (int k0 = 0; k0 < K; k0 += 64) {
    __syncthreads();                            // prev MFMA done with LDS
    #pragma unroll
    for (int it = 0; it < 4; it++) {            // A -> LDS via DMA
      int cc = it*256 + tid;
      int r = cc >> 3, s = cc & 7;
      int kk = k0 + (((s ^ (r & 7))) << 3);
      gload16((const u16*)A + (size_t)(m0 + r)*K + kk,
              As + (size_t)(it*256 + wbase)*8);
    }
    #pragma unroll
    for (int it = 0; it < 4; it++) {            // W (f16) -> LDS via DMA
      int cc = it*256 + tid;
      int r = cc >> 3, s = cc & 7;
      int kk = k0 + (((s ^ (r & 7))) << 3);
      gload16((const u16*)Wh + (size_t)(n0 + r)*K + kk,
              Bs + (size_t)(it*256 + wbase)*8);
    }
    __syncthreads();                            // drains DMA (vmcnt)
    #pragma unroll
    for (int ks = 0; ks < 2; ks++) {
      f16x8 af[4], bf[4];
      #pragma unroll
      for (int mi = 0; mi < 4; mi++) {
        int row = wm*64 + mi*16 + lr;
        int slot = (ks*4 + lg) ^ (row & 7);
        af[mi] = *(const f16x8*)&As[row*64 + slot*8];
      }
      #pragma unroll
      for (int ni = 0; ni < 4; ni++) {
        int row = wn*64 + ni*16 + lr;
        int slot = (ks*4 + lg) ^ (row & 7);
        bf[ni] = *(const f16x8*)&Bs[row*64 + slot*8];
      }
      #pragma unroll
      for (int mi = 0; mi < 4; mi++)
        #pragma unroll
        for (int ni = 0; ni < 4; ni++)
          acc[mi][ni] = __builtin_amdgcn_mfma_f32_16x16x32_f16(af[mi], bf[ni], acc[mi][ni], 0, 0, 0);
    }
  }
  __syncthreads();
  u16* Cst = lds;
  #pragma unroll
  for (int ni = 0; ni < 4; ni++) {
    int coln = wn*64 + ni*16 + lr;
    float bv = bias1[n0 + coln];
    if (bias2) bv += bias2[n0 + coln];
    #pragma unroll
    for (int mi = 0; mi < 4; mi++) {
      int rowm = wm*64 + mi*16 + lg*4;
      #pragma unroll
      for (int q = 0; q < 4; q++)
        Cst[(rowm + q)*136 + coln] = f2h(acc[mi][ni][q] + bv);
    }
  }
  __syncthreads();
  u16* Cg = (u16*)C;
  #pragma unroll
  for (int it = 0; it < 8; it++) {
    int idx = it*256 + tid;
    int r2 = idx >> 4, sg = idx & 15;
    uint4 v = *(const uint4*)&Cst[r2*136 + sg*8];
    *(uint4*)&Cg[(size_t)(m0 + r2)*N + n0 + sg*8] = v;
  }
}

__global__ __launch_bounds__(256) void k_gemm_mfma(
    const f16* __restrict__ A, const f16* __restrict__ Wh,
    const float* __restrict__ bias1, const float* __restrict__ bias2,
    f16* __restrict__ C, int M, int N, int K) {
  __shared__ __align__(16) u16 lds[128*136];
  gemm_body(A, Wh, bias1, bias2, C, M, N, K, blockIdx.y << 7, blockIdx.x << 7, lds);
}

// ---------------------------------------------------------------------------
// Dual A-sharing GEMM, M_TILE=256, XCD remap, DMA A-staging (r20).
// WF16=true: W also staged via DMA from pre-converted f16 image (dual2-2).
// ---------------------------------------------------------------------------
template<bool WF16>
__global__ __launch_bounds__(512) void k_gemm_dual2(
    const f16* __restrict__ A,
    const float* __restrict__ Wf, const float* __restrict__ Wb,
    const f16* __restrict__ Hf, const f16* __restrict__ Hb,
    const float* __restrict__ b1f, const float* __restrict__ b2f,
    const float* __restrict__ b1b, const float* __restrict__ b2b,
    f16* __restrict__ Cf, f16* __restrict__ Cb, int M, int N, int K) {
  __shared__ __align__(16) u16 lds[256*64 + 128*64];   // As | Bs ; Cst reuses
  u16* As = lds;
  u16* Bs = lds + 256*64;
  int tid = threadIdx.x;
  int wave = tid >> 6, lane = tid & 63;
  int wm = wave >> 1, wn = wave & 1;
  int lr = lane & 15, lg = lane >> 4;
  int stripes_per_xcd = M >> 11;
  int xcd = (int)blockIdx.x, y = (int)blockIdx.y;
  int sel = y & 7;
  int mstripe = xcd*stripes_per_xcd + (y >> 3);
  int which = sel >> 2;
  int n0 = (sel & 3) << 7;
  int m0 = mstripe << 8;
  const float* W  = which ? Wb : Wf;
  const f16*   Wh = which ? Hb : Hf;
  const float* b1 = which ? b1b : b1f;
  const float* b2 = which ? b2b : b2f;
  f16* C = which ? Cb : Cf;
  f32x4 acc[4][4];
  #pragma unroll
  for (int mi = 0; mi < 4; mi++)
    #pragma unroll
    for (int ni = 0; ni < 4; ni++)
      acc[mi][ni] = (f32x4){0.0f, 0.0f, 0.0f, 0.0f};
  int wbase = tid & ~63;
  for (int k0 = 0; k0 < K; k0 += 64) {
    float4 b_st[2][2];
    if constexpr (!WF16) {
      #pragma unroll
      for (int it = 0; it < 2; it++) {
        int cc = it*512 + tid;
        int r = cc >> 3, s = cc & 7;
        int kk = k0 + (((s ^ (r & 7))) << 3);
        const float* wp = W + (size_t)(n0 + r)*K + kk;
        b_st[it][0] = *(const float4*)wp;
        b_st[it][1] = *(const float4*)(wp + 4);
      }
    }
    __syncthreads();                            // prev MFMA done with LDS
    #pragma unroll
    for (int it = 0; it < 4; it++) {            // A -> LDS via DMA
      int cc = it*512 + tid;
      int r = cc >> 3, s = cc & 7;
      int kk = k0 + (((s ^ (r & 7))) << 3);
      gload16((const u16*)A + (size_t)(m0 + r)*K + kk,
              As + (size_t)(it*512 + wbase)*8);
    }
    if constexpr (WF16) {
      #pragma unroll
      for (int it = 0; it < 2; it++) {          // W (f16) -> LDS via DMA
        int cc = it*512 + tid;
        int r = cc >> 3, s = cc & 7;
        int kk = k0 + (((s ^ (r & 7))) << 3);
        gload16((const u16*)Wh + (size_t)(n0 + r)*K + kk,
                Bs + (size_t)(it*512 + wbase)*8);
      }
    } else {
      #pragma unroll
      for (int it = 0; it < 2; it++) {          // W regs -> LDS (f16)
        int cc = it*512 + tid;
        union { uint4 u; f16 h[8]; } bb;
        float4 x = b_st[it][0], y2 = b_st[it][1];
        bb.h[0] = (f16)x.x;  bb.h[1] = (f16)x.y;  bb.h[2] = (f16)x.z;  bb.h[3] = (f16)x.w;
        bb.h[4] = (f16)y2.x; bb.h[5] = (f16)y2.y; bb.h[6] = (f16)y2.z; bb.h[7] = (f16)y2.w;
        *(uint4*)&Bs[cc*8] = bb.u;
      }
    }
    __syncthreads();                            // drains DMA (vmcnt) + ds
    #pragma unroll
    for (int ks = 0; ks < 2; ks++) {
      f16x8 af[4], bf[4];
      #pragma unroll
      for (int mi = 0; mi < 4; mi++) {
        int row = wm*64 + mi*16 + lr;
        int slot = (ks*4 + lg) ^ (row & 7);
        af[mi] = *(const f16x8*)&As[row*64 + slot*8];
      }
      #pragma unroll
      for (int ni = 0; ni < 4; ni++) {
        int row = wn*64 + ni*16 + lr;
        int slot = (ks*4 + lg) ^ (row & 7);
        bf[ni] = *(const f16x8*)&Bs[row*64 + slot*8];
      }
      #pragma unroll
      for (int mi = 0; mi < 4; mi++)
        #pragma unroll
        for (int ni = 0; ni < 4; ni++)
          acc[mi][ni] = __builtin_amdgcn_mfma_f32_16x16x32_f16(af[mi], bf[ni], acc[mi][ni], 0, 0, 0);
    }
  }
  u16* Cst = lds;
  u16* Cg = (u16*)C;
  #pragma unroll
  for (int half = 0; half < 2; half++) {
    __syncthreads();
    if (wm == half*2 || wm == half*2 + 1) {
      int lwm = wm - half*2;
      #pragma unroll
      for (int ni = 0; ni < 4; ni++) {
        int coln = wn*64 + ni*16 + lr;
        float bv = b1[n0 + coln];
        if (b2) bv += b2[n0 + coln];
        #pragma unroll
        for (int mi = 0; mi < 4; mi++) {
          int rowm = lwm*64 + mi*16 + lg*4;
          #pragma unroll
          for (int q = 0; q < 4; q++)
            Cst[(rowm + q)*136 + coln] = f2h(acc[mi][ni][q] + bv);
        }
      }
    }
    __syncthreads();
    #pragma unroll
    for (int it = 0; it < 4; it++) {
      int idx = it*512 + tid;
      int r2 = idx >> 4, sg = idx & 15;
      uint4 v = *(const uint4*)&Cst[r2*136 + sg*8];
      *(uint4*)&Cg[(size_t)(m0 + half*128 + r2)*N + n0 + sg*8] = v;
    }
  }
}

// ---------------------------------------------------------------------------
// LSTM recurrence via MFMA.  4 seqs/block.  (validated r14)
// ---------------------------------------------------------------------------
__global__ __launch_bounds__(512) void k_lstm_mfma(
    const f16* __restrict__ pre_f, const f16* __restrict__ pre_b,
    const float* __restrict__ whh_f, const float* __restrict__ whh_b,
    f16* __restrict__ hout) {
  __shared__ __align__(16) u16 hlh[16*136];
  __shared__ float gl[4*516];
  int tid = threadIdx.x;
  int dir = blockIdx.x & 1;
  int b0  = (blockIdx.x >> 1) << 2;
  const f16* pre = dir ? pre_b : pre_f;
  const float* whh = dir ? whh_b : whh_f;
  int wave = tid >> 6, lane = tid & 63;
  int lr = lane & 15, lg = lane >> 4;
  f16x8 bw[4][4];
  #pragma unroll
  for (int nt = 0; nt < 4; nt++) {
    int j = (wave*4 + nt)*16 + lr;
    #pragma unroll
    for (int kb = 0; kb < 4; kb++) {
      const float* wp = whh + (size_t)j*128 + kb*32 + lg*8;
      f16x8 v;
      #pragma unroll
      for (int e = 0; e < 8; e++) v[e] = (f16)wp[e];
      bw[nt][kb] = v;
    }
  }
  for (int i = tid; i < 16*136; i += 512) hlh[i] = 0;
  int s_a = tid >> 7;
  int u   = tid & 127;
  size_t prow = (size_t)(b0 + s_a)*128;
  const u16* preu = (const u16*)pre;
  int t0 = dir ? 127 : 0;
  u16 pi = preu[(prow + t0)*512 + u];
  u16 pf = preu[(prow + t0)*512 + 128 + u];
  u16 pg = preu[(prow + t0)*512 + 256 + u];
  u16 po = preu[(prow + t0)*512 + 384 + u];
  float c = 0.0f;
  u16* houtu = (u16*)hout;
  __syncthreads();
  for (int s = 0; s < 128; s++) {
    int t = dir ? (127 - s) : s;
    f16x8 af[4];
    #pragma unroll
    for (int kb = 0; kb < 4; kb++)
      af[kb] = *(const f16x8*)&hlh[lr*136 + kb*32 + lg*8];
    #pragma unroll
    for (int nt = 0; nt < 4; nt++) {
      f32x4 acc = {0.0f, 0.0f, 0.0f, 0.0f};
      #pragma unroll
      for (int kb = 0; kb < 4; kb++)
        acc = __builtin_amdgcn_mfma_f32_16x16x32_f16(af[kb], bw[nt][kb], acc, 0, 0, 0);
      if (lg == 0) {
        int jc = (wave*4 + nt)*16 + lr;
        #pragma unroll
        for (int q = 0; q < 4; q++)
          gl[q*516 + jc] = acc[q];
      }
    }
    __syncthreads();
    float gi = gl[s_a*516 + u];
    float gf = gl[s_a*516 + 128 + u];
    float gg = gl[s_a*516 + 256 + u];
    float go = gl[s_a*516 + 384 + u];
    u16 ni = pi, nf = pf, ng = pg, no = po;
    if (s < 127) {
      int tn = dir ? (126 - s) : (s + 1);
      pi = preu[(prow + tn)*512 + u];
      pf = preu[(prow + tn)*512 + 128 + u];
      pg = preu[(prow + tn)*512 + 256 + u];
      po = preu[(prow + tn)*512 + 384 + u];
    }
    float iv = gi + h2fu(ni), fv = gf + h2fu(nf);
    float gv = gg + h2fu(ng), ov = go + h2fu(no);
    c = sigmf(fv)*c + sigmf(iv)*tanhfast(gv);
    float hv = sigmf(ov)*tanhfast(c);
    u16 hw = f2h(hv);
    hlh[s_a*136 + u] = hw;
    houtu[(prow + t)*256 + (dir << 7) + u] = hw;
    __syncthreads();
  }
}

// ---------------------------------------------------------------------------
// MHA via MFMA.  (unchanged — validated round 10)
// ---------------------------------------------------------------------------
__global__ __launch_bounds__(256) void k_mha_mfma(const f16* __restrict__ qkv, f16* __restrict__ o) {
  __shared__ __align__(16) u16 smemA[128*144];
  __shared__ __align__(16) u16 vt[64*136];
  int b = blockIdx.x, h = blockIdx.y, tid = threadIdx.x;
  int wave = tid >> 6, lane = tid & 63;
  int lr = lane & 15, lg = lane >> 4;
  u16* qs = smemA;
  u16* ks = smemA + 128*72;
  const u16* base = (const u16*)(qkv + (size_t)b*98304 + h*64);
  const u32* base32 = (const u32*)base;
  for (int i = tid; i < 4096; i += 256) {
    int t = i >> 5, d2 = i & 31;
    *(u32*)&qs[t*72 + (d2 << 1)] = base32[t*384 + d2];
    *(u32*)&ks[t*72 + (d2 << 1)] = base32[t*384 + 128 + d2];
  }
  for (int i = tid; i < 8192; i += 256) {
    int t = i >> 6, d = i & 63;
    vt[d*136 + t] = base[t*768 + 512 + d];
  }
  __syncthreads();
  f32x4 sacc[2][8];
  {
    f16x8 aq[2][2];
    #pragma unroll
    for (int mi = 0; mi < 2; mi++) {
      int mt = wave*2 + mi;
      #pragma unroll
      for (int kb = 0; kb < 2; kb++)
        aq[mi][kb] = *(const f16x8*)&qs[(mt*16 + lr)*72 + kb*32 + lg*8];
    }
    #pragma unroll
    for (int mi = 0; mi < 2; mi++)
      #pragma unroll
      for (int nt = 0; nt < 8; nt++) {
        f32x4 acc = {0.0f, 0.0f, 0.0f, 0.0f};
        #pragma unroll
        for (int kb = 0; kb < 2; kb++) {
          f16x8 bf = *(const f16x8*)&ks[(nt*16 + lr)*72 + kb*32 + lg*8];
          acc = __builtin_amdgcn_mfma_f32_16x16x32_f16(aq[mi][kb], bf, acc, 0, 0, 0);
        }
        sacc[mi][nt] = acc;
      }
  }
  __syncthreads();
  u16* ps = smemA;
  #pragma unroll
  for (int mi = 0; mi < 2; mi++) {
    int rb = (wave*2 + mi)*16 + lg*4;
    #pragma unroll
    for (int q = 0; q < 4; q++) {
      float pv[8]; float mx = -1e30f;
      #pragma unroll
      for (int nt = 0; nt < 8; nt++) { float v = sacc[mi][nt][q]*0.125f; pv[nt] = v; mx = fmaxf(mx, v); }
      mx = fmaxf(mx, __shfl_xor(mx, 1));
      mx = fmaxf(mx, __shfl_xor(mx, 2));
      mx = fmaxf(mx, __shfl_xor(mx, 4));
      mx = fmaxf(mx, __shfl_xor(mx, 8));
      float sum = 0.0f;
      #pragma unroll
      for (int nt = 0; nt < 8; nt++) { float e = __expf(pv[nt] - mx); pv[nt] = e; sum += e; }
      sum += __shfl_xor(sum, 1);
      sum += __shfl_xor(sum, 2);
      sum += __shfl_xor(sum, 4);
      sum += __shfl_xor(sum, 8);
      float inv = 1.0f/sum;
      #pragma unroll
      for (int nt = 0; nt < 8; nt++)
        ps[(rb + q)*136 + nt*16 + lr] = f2h(pv[nt]*inv);
    }
  }
  __syncthreads();
  f32x4 oacc[2][4];
  {
    f16x8 ap[2][4];
    #pragma unroll
    for (int mi = 0; mi < 2; mi++) {
      int mt = wave*2 + mi;
      #pragma unroll
      for (int kb = 0; kb < 4; kb++)
        ap[mi][kb] = *(const f16x8*)&ps[(mt*16 + lr)*136 + kb*32 + lg*8];
    }
    #pragma unroll
    for (int mi = 0; mi < 2; mi++)
      #pragma unroll
      for (int nt = 0; nt < 4; nt++) {
        f32x4 acc = {0.0f, 0.0f, 0.0f, 0.0f};
        #pragma unroll
        for (int kb = 0; kb < 4; kb++) {
          f16x8 bf = *(const f16x8*)&vt[(nt*16 + lr)*136 + kb*32 + lg*8];
          acc = __builtin_amdgcn_mfma_f32_16x16x32_f16(ap[mi][kb], bf, acc, 0, 0, 0);
        }
        oacc[mi][nt] = acc;
      }
  }
  u16* og = (u16*)o;
  #pragma unroll
  for (int mi = 0; mi < 2; mi++) {
    int rb = (wave*2 + mi)*16 + lg*4;
    #pragma unroll
    for (int nt = 0; nt < 4; nt++) {
      int col = h*64 + nt*16 + lr;
      #pragma unroll
      for (int q = 0; q < 4; q++)
        og[((size_t)b*128 + rb + q)*256 + col] = f2h(oacc[mi][nt][q]);
    }
  }
}

// ---------------------------------------------------------------------------
// att = LayerNorm(mha_out + lstm_out), width 256.  (unchanged)
// ---------------------------------------------------------------------------
__global__ __launch_bounds__(256) void k_lnres(
    const f16* __restrict__ a, const f16* __restrict__ r,
    const float* __restrict__ g, const float* __restrict__ bb, f16* __restrict__ out) {
  int row = blockIdx.x*4 + (threadIdx.x >> 6);
  int lane = threadIdx.x & 63;
  const f16* ar = a + (size_t)row*256 + lane*4;
  const f16* rr = r + (size_t)row*256 + lane*4;
  float v0 = (float)ar[0] + (float)rr[0];
  float v1 = (float)ar[1] + (float)rr[1];
  float v2 = (float)ar[2] + (float)rr[2];
  float v3 = (float)ar[3] + (float)rr[3];
  float s = v0 + v1 + v2 + v3;
  float q = v0*v0 + v1*v1 + v2*v2 + v3*v3;
  #pragma unroll
  for (int off = 32; off; off >>= 1) { s += __shfl_xor(s, off); q += __shfl_xor(q, off); }
  float mean = s*(1.0f/256.0f);
  float var  = q*(1.0f/256.0f) - mean*mean;
  float rstd = rsqrtf(var + 1e-5f);
  int d0 = lane*4;
  f16* op = out + (size_t)row*256 + d0;
  op[0] = (f16)((v0 - mean)*rstd*g[d0+0] + bb[d0+0]);
  op[1] = (f16)((v1 - mean)*rstd*g[d0+1] + bb[d0+1]);
  op[2] = (f16)((v2 - mean)*rstd*g[d0+2] + bb[d0+2]);
  op[3] = (f16)((v3 - mean)*rstd*g[d0+3] + bb[d0+3]);
}

// ---------------------------------------------------------------------------
// mean/max pool over T, LayerNorm(512), cls1+ReLU, cls2.  (unchanged)
// ---------------------------------------------------------------------------
__global__ __launch_bounds__(512) void k_pool_cls(
    const f16* __restrict__ att, const float* __restrict__ png, const float* __restrict__ pnb,
    const float* __restrict__ w1, const float* __restrict__ b1,
    const float* __restrict__ w2, const float* __restrict__ b2, float* __restrict__ out) {
  __shared__ float pl[512];
  __shared__ float redS[8], redQ[8];
  __shared__ float mrv[2];
  __shared__ float hl[128];
  int b = blockIdx.x, tid = threadIdx.x;
  if (tid < 256) {
    const f16* ar = att + (size_t)b*32768 + tid;
    float s = 0.0f, mx = -1e30f;
    for (int t = 0; t < 128; t++) { float v = (float)ar[t*256]; s += v; mx = fmaxf(mx, v); }
    pl[tid] = s*(1.0f/128.0f);
    pl[256 + tid] = mx;
  }
  __syncthreads();
  float v = pl[tid];
  float s = v, q = v*v;
  #pragma unroll
  for (int off = 32; off; off >>= 1) { s += __shfl_xor(s, off); q += __shfl_xor(q, off); }
  if ((tid & 63) == 0) { redS[tid >> 6] = s; redQ[tid >> 6] = q; }
  __syncthreads();
  if (tid == 0) {
    float S = 0.0f, Q = 0.0f;
    #pragma unroll
    for (int w = 0; w < 8; w++) { S += redS[w]; Q += redQ[w]; }
    float mean = S*(1.0f/512.0f);
    float var  = Q*(1.0f/512.0f) - mean*mean;
    mrv[0] = mean; mrv[1] = rsqrtf(var + 1e-5f);
  }
  __syncthreads();
  pl[tid] = (v - mrv[0])*mrv[1]*png[tid] + pnb[tid];
  __syncthreads();
  if (tid < 128) {
    float acc = b1[tid];
    const float* wrp = w1 + (size_t)tid*512;
    for (int d = 0; d < 512; d++) acc += pl[d]*wrp[d];
    hl[tid] = fmaxf(acc, 0.0f)*w2[tid];
  }
  __syncthreads();
  if (tid < 64) {
    float rsum = hl[tid] + hl[tid + 64];
    #pragma unroll
    for (int off = 32; off; off >>= 1) rsum += __shfl_xor(rsum, off);
    if (tid == 0) out[b] = rsum + b2[0];
  }
}

// ---------------------------------------------------------------------------
extern "C" void kernel_launch(void* const* d_in, const int* in_sizes, int n_in,
                              void* d_out, int out_size, void* d_ws, size_t ws_size,
                              hipStream_t stream) {
  (void)in_sizes; (void)n_in; (void)out_size;
  if (ws_size < (size_t)192*1024*1024) return;
  const float* IN[47];
  for (int i = 0; i < 47; i++) IN[i] = (const float*)d_in[i];
  char* W8 = (char*)d_ws;
  f16* feat     = (f16*)(W8 + ((size_t)0  << 20));  // [0,64)
  f16* g        = (f16*)(W8 + ((size_t)64 << 20));  // [64,192)
  f16* pre_f    = (f16*)(W8 + ((size_t)0  << 20));  // [0,32)
  f16* pre_b    = (f16*)(W8 + ((size_t)32 << 20));  // [32,64)
  f16* h1       = (f16*)(W8 + ((size_t)64 << 20));  // [64,80)
  f16* lstm_out = (f16*)(W8 + ((size_t)80 << 20));  // [80,96)
  f16* qkv      = (f16*)(W8 + ((size_t)96 << 20));  // [96,144)
  f16* o_flat   = (f16*)(W8 + ((size_t)0  << 20));  // [0,16)
  f16* mo       = (f16*)(W8 + ((size_t)16 << 20));  // [16,32)
  f16* att      = (f16*)(W8 + ((size_t)32 << 20));  // [32,48)
  // wt2p: feat region — dead after gat<64>, overwritten by pre_f later (r27).
  u16* wt2p     = (u16*)W8;
  // f16 W images in [144,192): dead forever once dual2-1 retires g.
  f16* l1fW = (f16*)(W8 + ((size_t)144 << 20));   // 256 KB
  f16* l1bW = (f16*)(W8 + ((size_t)145 << 20));   // 256 KB
  f16* qkvW = (f16*)(W8 + ((size_t)146 << 20));   // 384 KB
  f16* moW  = (f16*)(W8 + ((size_t)147 << 20));   // 128 KB

  k_conv<<<4096, 256, 0, stream>>>(IN[0], IN[1], IN[2], IN[3], IN[4],
                                   IN[5], IN[6], IN[7], IN[8], feat);
  k_gat_mfma<64, false><<<4096, 512, 0, stream>>>(IN[9], nullptr, feat,
                                                  IN[10], IN[11], IN[12], IN[13], g);
  k_prep_gat2<<<68, 256, 0, stream>>>(IN[14], wt2p);
  k_gat_mfma<128, true><<<4096, 512, 0, stream>>>(nullptr, (const f16*)wt2p, g,
                                                  IN[15], IN[16], IN[17], IN[18], g);
  k_gemm_dual2<false><<<dim3(8, 128), 512, 0, stream>>>(g, IN[19], IN[23], nullptr, nullptr,
                                                 IN[21], IN[22], IN[25], IN[26],
                                                 pre_f, pre_b, 32768, 512, 2048);
  k_prep_w<<<128, 256, 0, stream>>>(IN[27], IN[31], IN[35], IN[37],
                                    (u16*)l1fW, (u16*)l1bW, (u16*)qkvW, (u16*)moW);
  k_lstm_mfma<<<128, 512, 0, stream>>>(pre_f, pre_b, IN[20], IN[24], h1);
  k_gemm_dual2<true><<<dim3(8, 128), 512, 0, stream>>>(h1, nullptr, nullptr, l1fW, l1bW,
                                                 IN[29], IN[30], IN[33], IN[34],
                                                 pre_f, pre_b, 32768, 512, 256);
  k_lstm_mfma<<<128, 512, 0, stream>>>(pre_f, pre_b, IN[28], IN[32], lstm_out);
  k_gemm_mfma<<<dim3(6, 256), 256, 0, stream>>>(lstm_out, qkvW, IN[36], nullptr, qkv, 32768, 768, 256);
  k_mha_mfma<<<dim3(256, 4), 256, 0, stream>>>(qkv, o_flat);
  k_gemm_mfma<<<dim3(2, 256), 256, 0, stream>>>(o_flat, moW, IN[38], nullptr, mo, 32768, 256, 256);
  k_lnres<<<8192, 256, 0, stream>>>(mo, lstm_out, IN[39], IN[40], att);
  k_pool_cls<<<256, 512, 0, stream>>>(att, IN[41], IN[42], IN[43], IN[44], IN[45], IN[46],
                                      (float*)d_out);
}

// Round 31
// 833.028 us; speedup vs baseline: 1.0124x; 1.0124x over previous
//
#include <hip/hip_runtime.h>
#include <hip/hip_bf16.h>

typedef _Float16 f16;
typedef unsigned short u16;
typedef unsigned int   u32;
typedef __attribute__((ext_vector_type(8))) _Float16 f16x8;
typedef __attribute__((ext_vector_type(4))) float    f32x4;

__device__ __forceinline__ float h2fu(u16 u) { union { u16 s; f16 h; } t; t.s = u; return (float)t.h; }
__device__ __forceinline__ u16   f2h(float f) { union { u16 s; f16 h; } t; t.h = (f16)f; return t.s; }
__device__ __forceinline__ float geluf(float u) { return 0.5f*u*(1.0f + erff(u*0.70710678118654752f)); }
__device__ __forceinline__ float sigmf(float x) { return 1.0f/(1.0f + __expf(-x)); }
__device__ __forceinline__ float tanhfast(float x) { return 1.0f - 2.0f/(__expf(2.0f*x) + 1.0f); }

// async global->LDS DMA, 16 bytes/lane; lds base must be wave-uniform.
__device__ __forceinline__ void gload16(const void* gp, void* lp) {
  __builtin_amdgcn_global_load_lds(
      (const __attribute__((address_space(1))) u32*)gp,
      (__attribute__((address_space(3))) u32*)lp, 16, 0, 0);
}

// ---------------------------------------------------------------------------
// One-shot prep for gat<128>: W^T in f16 with the PAD BAKED IN (128 rows of
// 136, cols [128,136) zero).  Lives at W8+0 (feat region — dead after gat<64>).
// ---------------------------------------------------------------------------
__global__ __launch_bounds__(256) void k_prep_gat2(
    const float* __restrict__ g2w, u16* __restrict__ wt2p) {
  int i = blockIdx.x*256 + threadIdx.x;   // 68 blocks * 256 = 17408 exactly
  int c = i/136, k = i%136;
  wt2p[i] = (k < 128) ? f2h(g2w[k*128 + c]) : (u16)0;
}

// ---------------------------------------------------------------------------
// Fused conv1(1->32,k7,p3)+bn+gelu -> conv2 via SPLIT-K im2col MFMA.
// (exact r24/r27-validated form: in-kernel W conversion)
// ---------------------------------------------------------------------------
__global__ __launch_bounds__(256) void k_conv(
    const float* __restrict__ x,
    const float* __restrict__ w1, const float* __restrict__ cb1v,
    const float* __restrict__ g1v, const float* __restrict__ be1v,
    const float* __restrict__ w2, const float* __restrict__ cb2v,
    const float* __restrict__ g2v, const float* __restrict__ be2v,
    f16* __restrict__ feat) {
  __shared__ float xs[262];
  __shared__ __align__(16) u16 xcol[128*104];   // per-half im2col [t2][icl*5+kk]
  __shared__ __align__(16) u16 wcol[64*184];    // [oc][ic*5+kk], stride 184
  __shared__ float w1l[224];
  __shared__ float cb1[32], sc1[32], sb1[32];
  __shared__ float cb2[64], sc2[64], sb2[64];
  int r = blockIdx.x, tid = threadIdx.x;
  int bb = r >> 4, n = r & 15;
  for (int i = tid; i < 262; i += 256) {
    int p = i - 3;
    xs[i] = (p >= 0 && p < 256) ? x[(size_t)r*256 + p] : 0.0f;
  }
  if (tid < 224) {
    w1l[tid] = w1[tid];
  } else {
    int oc = tid - 224;
    cb1[oc] = cb1v[oc];
    sc1[oc] = g1v[oc] * rsqrtf(1.0f + 1e-5f);
    sb1[oc] = be1v[oc];
  }
  for (int i = tid; i < 10240; i += 256) {
    int oc = i/160, c = i%160;
    wcol[oc*184 + c] = f2h(w2[i]);
  }
  for (int i = tid; i < 64*24; i += 256) {       // zero wcol cols [160,184)
    int oc = i/24, c = 160 + i%24;
    wcol[oc*184 + c] = 0;
  }
  if (tid < 64) {
    cb2[tid] = cb2v[tid];
    sc2[tid] = g2v[tid] * rsqrtf(1.0f + 1e-5f);
    sb2[tid] = be2v[tid];
  }
  // zero xcol K-pad cols [80,96) for all rows (persist across halves)
  for (int i = tid; i < 2048; i += 256) {
    int row = i >> 4, c = 80 + (i & 15);
    xcol[row*104 + c] = 0;
  }
  // zero boundary cells (never scatter-written): t2=0 kk in {0,1}; t2=127 kk=4
  if (tid < 48) {
    if (tid < 32) { int icl = tid >> 1, kk = tid & 1; xcol[icl*5 + kk] = 0; }
    else          { int icl = tid - 32; xcol[127*104 + icl*5 + 4] = 0; }
  }
  __syncthreads();                               // B1
  float xv[7];
  #pragma unroll
  for (int k = 0; k < 7; k++) xv[k] = xs[tid + k];
  int offs[3]; int noff = 0;
  #pragma unroll
  for (int j = 0; j < 3; j++) {
    int kk = (tid & 1) + 2*j;
    if (kk < 5) {
      int t2 = (tid + 2 - kk) >> 1;
      if (t2 >= 0 && t2 < 128) { offs[noff] = t2*104 + kk; noff++; }
    }
  }
  int wave = tid >> 6, lane = tid & 63;
  int lr = lane & 15, lg = lane >> 4;
  f32x4 acc[2][4];
  #pragma unroll
  for (int mi = 0; mi < 2; mi++)
    #pragma unroll
    for (int nt = 0; nt < 4; nt++)
      acc[mi][nt] = (f32x4){0.0f, 0.0f, 0.0f, 0.0f};
  #pragma unroll
  for (int h = 0; h < 2; h++) {
    for (int icl = 0; icl < 16; icl++) {
      int oc = h*16 + icl;
      float a = cb1[oc];
      #pragma unroll
      for (int k = 0; k < 7; k++) a += w1l[oc*7 + k]*xv[k];
      u16 hv = f2h(geluf(a*sc1[oc] + sb1[oc]));
      for (int i2 = 0; i2 < noff; i2++) xcol[offs[i2] + icl*5] = hv;
    }
    __syncthreads();                             // scatter done
    f16x8 af[2][3];
    #pragma unroll
    for (int mi = 0; mi < 2; mi++)
      #pragma unroll
      for (int kb = 0; kb < 3; kb++)
        af[mi][kb] = *(const f16x8*)&xcol[((wave*2 + mi)*16 + lr)*104 + kb*32 + lg*8];
    #pragma unroll
    for (int nt = 0; nt < 4; nt++) {
      f16x8 bf[3];
      #pragma unroll
      for (int kb = 0; kb < 3; kb++)
        bf[kb] = *(const f16x8*)&wcol[(nt*16 + lr)*184 + h*80 + kb*32 + lg*8];
      #pragma unroll
      for (int mi = 0; mi < 2; mi++)
        #pragma unroll
        for (int kb = 0; kb < 3; kb++)
          acc[mi][nt] = __builtin_amdgcn_mfma_f32_16x16x32_f16(af[mi][kb], bf[kb], acc[mi][nt], 0, 0, 0);
    }
    if (h == 0) __syncthreads();                 // MFMA reads done before half-1 scatter
  }
  #pragma unroll
  for (int nt = 0; nt < 4; nt++) {
    int oc = nt*16 + lr;
    float c2 = cb2[oc], s2 = sc2[oc], b2 = sb2[oc];
    #pragma unroll
    for (int mi = 0; mi < 2; mi++) {
      #pragma unroll
      for (int q = 0; q < 4; q++) {
        int t2 = (wave*2 + mi)*16 + lg*4 + q;
        float u = (acc[mi][nt][q] + c2)*s2 + b2;
        feat[(((size_t)bb*128 + t2)*16 + n)*64 + oc] = (f16)geluf(u);
      }
    }
  }
}

// ---------------------------------------------------------------------------
// GAT layer (+ReLU +LayerNorm), LDS-aliased, 3 barriers (r22/r24-validated).
// DW=false: W staged f32->f16 into LDS per block.
// DW=true : W staged via linear gload16 DMA from pre-padded f16 image. (r27)
// ---------------------------------------------------------------------------
template<int F, bool DW>
__global__ __launch_bounds__(512) void k_gat_mfma(
    const float* __restrict__ W, const f16* __restrict__ Wt,
    const f16* __restrict__ xin,
    const float* __restrict__ asrc, const float* __restrict__ adst,
    const float* __restrict__ gng, const float* __restrict__ gnb,
    f16* __restrict__ gout) {
  constexpr int XP = F + 8;
  constexpr int ASZ = (128*XP > 512*24) ? 128*XP : 512*24;   // xa | alx
  constexpr int BSZ = 128*144;                               // wt | hT
  __shared__ __align__(16) u16 regA[ASZ];
  __shared__ __align__(16) u16 regB[BSZ];
  __shared__ float esl[512], edl[512];
  __shared__ float wsv[128], wdv[128], gngl[128], gnbl[128];
  u16* xa  = regA;
  u16* alx = regA;
  u16* wt  = regB;
  u16* hT  = regB;
  int tid = threadIdx.x;
  size_t rowbase = (size_t)blockIdx.x*128;
  const u32* xg = (const u32*)(xin + rowbase*F);
  if constexpr (DW) {
    int wbase = tid & ~63;
    #pragma unroll
    for (int it = 0; it < 4; it++) {
      int cc = it*512 + tid;
      gload16((const u16*)Wt + cc*8, wt + (size_t)(it*512 + wbase)*8);
    }
    if (tid < 128)
      gload16((const u16*)Wt + (2048 + tid)*8, wt + (size_t)(2048 + wbase)*8);
  }
  for (int i = tid; i < 128*F/2; i += 512) {
    u32 v = xg[i];
    int r = (2*i)/F, k = (2*i)%F;
    *(u32*)&xa[r*XP + k] = v;
  }
  if constexpr (!DW) {
    for (int i = tid; i < F*128; i += 512) {
      int k = i >> 7, c = i & 127;
      wt[c*XP + k] = f2h(W[i]);
    }
  }
  if (tid < 128) {
    wsv[tid] = asrc[tid]; wdv[tid] = adst[tid];
    gngl[tid] = gng[tid]; gnbl[tid] = gnb[tid];
  }
  __syncthreads();                 // B1 (drains DMA vmcnt)
  int wave = tid >> 6, lane = tid & 63;
  int lr = lane & 15, lg = lane >> 4;
  int g = wave;
  f32x4 dacc[8];
  {
    f16x8 af[F/32];
    #pragma unroll
    for (int kb = 0; kb < F/32; kb++)
      af[kb] = *(const f16x8*)&xa[(g*16 + lr)*XP + kb*32 + lg*8];
    #pragma unroll
    for (int nt = 0; nt < 8; nt++) {
      f32x4 a = {0.0f, 0.0f, 0.0f, 0.0f};
      #pragma unroll
      for (int kb = 0; kb < F/32; kb++) {
        f16x8 bf = *(const f16x8*)&wt[(nt*16 + lr)*XP + kb*32 + lg*8];
        a = __builtin_amdgcn_mfma_f32_16x16x32_f16(af[kb], bf, a, 0, 0, 0);
      }
      dacc[nt] = a;
    }
  }
  #pragma unroll
  for (int q = 0; q < 4; q++) {
    #pragma unroll
    for (int hh = 0; hh < 4; hh++) {
      float es = dacc[2*hh][q]*wsv[hh*32 + lr] + dacc[2*hh+1][q]*wsv[hh*32 + 16 + lr];
      float ed = dacc[2*hh][q]*wdv[hh*32 + lr] + dacc[2*hh+1][q]*wdv[hh*32 + 16 + lr];
      es += __shfl_xor(es, 1); es += __shfl_xor(es, 2);
      es += __shfl_xor(es, 4); es += __shfl_xor(es, 8);
      ed += __shfl_xor(ed, 1); ed += __shfl_xor(ed, 2);
      ed += __shfl_xor(ed, 4); ed += __shfl_xor(ed, 8);
      if (lr == 0) {
        int nn = lg*4 + q;
        esl[g*64 + nn*4 + hh] = es;
        edl[g*64 + nn*4 + hh] = ed;
      }
    }
  }
  __syncthreads();                 // B2: all reads of xa (regA) / wt (regB) done
  #pragma unroll
  for (int nt = 0; nt < 8; nt++) {
    int col = nt*16 + lr;
    ushort4 hv;
    hv.x = f2h(dacc[nt][0]); hv.y = f2h(dacc[nt][1]);
    hv.z = f2h(dacc[nt][2]); hv.w = f2h(dacc[nt][3]);
    *(ushort4*)&hT[col*144 + g*16 + lg*4] = hv;
  }
  for (int z = lane; z < 256; z += 64) {
    int col = g*16 + (z >> 4);
    hT[col*144 + 128 + (z & 15)] = 0;
  }
  {
    int i = lr, hh = lg;
    float ei = esl[g*64 + i*4 + hh];
    float pv[16]; float mx = -1e30f;
    #pragma unroll
    for (int j = 0; j < 16; j++) {
      float e = ei + edl[g*64 + j*4 + hh];
      e = (e < 0.0f) ? 0.2f*e : e;
      pv[j] = e; mx = fmaxf(mx, e);
    }
    float sum = 0.0f;
    #pragma unroll
    for (int j = 0; j < 16; j++) { float pe = __expf(pv[j] - mx); pv[j] = pe; sum += pe; }
    float inv = 1.0f/sum;
    u16* ap = &alx[((g*4 + hh)*16 + i)*24];
    #pragma unroll
    for (int j = 0; j < 16; j++) ap[j] = f2h(pv[j]*inv);
  }
  __syncthreads();                 // B3: hT/alx fully written before PV reads
  f32x4 oacc[4][2];
  #pragma unroll
  for (int hh = 0; hh < 4; hh++) {
    f16x8 pa = {};
    if (lg < 2) pa = *(const f16x8*)&alx[((g*4 + hh)*16 + lr)*24 + lg*8];
    #pragma unroll
    for (int nh = 0; nh < 2; nh++) {
      f16x8 bv = *(const f16x8*)&hT[(hh*32 + nh*16 + lr)*144 + g*16 + lg*8];
      f32x4 z = {0.0f, 0.0f, 0.0f, 0.0f};
      oacc[hh][nh] = __builtin_amdgcn_mfma_f32_16x16x32_f16(pa, bv, z, 0, 0, 0);
    }
  }
  #pragma unroll
  for (int q = 0; q < 4; q++) {
    float v[8];
    float s = 0.0f, sq = 0.0f;
    #pragma unroll
    for (int hh = 0; hh < 4; hh++)
      #pragma unroll
      for (int nh = 0; nh < 2; nh++) {
        float t = fmaxf(oacc[hh][nh][q], 0.0f);
        v[hh*2 + nh] = t; s += t; sq += t*t;
      }
    s  += __shfl_xor(s, 1);  sq += __shfl_xor(sq, 1);
    s  += __shfl_xor(s, 2);  sq += __shfl_xor(sq, 2);
    s  += __shfl_xor(s, 4);  sq += __shfl_xor(sq, 4);
    s  += __shfl_xor(s, 8);  sq += __shfl_xor(sq, 8);
    float mean = s*(1.0f/128.0f);
    float var  = sq*(1.0f/128.0f) - mean*mean;
    float rstd = rsqrtf(var + 1e-5f);
    size_t row = rowbase + g*16 + lg*4 + q;
    u16* orow = (u16*)(gout + row*128);
    #pragma unroll
    for (int hh = 0; hh < 4; hh++)
      #pragma unroll
      for (int nh = 0; nh < 2; nh++) {
        int col = hh*32 + nh*16 + lr;
        orow[col] = f2h((v[hh*2 + nh] - mean)*rstd*gngl[col] + gnbl[col]);
      }
  }
}

// ---------------------------------------------------------------------------
// MFMA GEMM core (f32 W, 128-m-tile) with DMA A-staging.  (validated r29)
// ---------------------------------------------------------------------------
__device__ __forceinline__ void gemm_body(
    const f16* __restrict__ A, const float* __restrict__ W,
    const float* __restrict__ bias1, const float* __restrict__ bias2,
    f16* __restrict__ C, int M, int N, int K, int m0, int n0, u16* lds) {
  u16* As = lds;
  u16* Bs = lds + 128*64;
  int tid = threadIdx.x;
  int wave = tid >> 6, lane = tid & 63;
  int wm = wave >> 1, wn = wave & 1;
  int lr = lane & 15, lg = lane >> 4;
  int wbase = tid & ~63;
  f32x4 acc[4][4];
  #pragma unroll
  for (int mi = 0; mi < 4; mi++)
    #pragma unroll
    for (int ni = 0; ni < 4; ni++)
      acc[mi][ni] = (f32x4){0.0f, 0.0f, 0.0f, 0.0f};
  for (int k0 = 0; k0 < K; k0 += 64) {
    float4 b_st[4][2];
    #pragma unroll
    for (int it = 0; it < 4; it++) {            // W -> regs (cvt path)
      int cc = it*256 + tid;
      int r = cc >> 3, s = cc & 7;
      int kk = k0 + (((s ^ (r & 7))) << 3);
      const float* wp = W + (size_t)(n0 + r)*K + kk;
      b_st[it][0] = *(const float4*)wp;
      b_st[it][1] = *(const float4*)(wp + 4);
    }
    __syncthreads();                            // prev MFMA done with LDS
    #pragma unroll
    for (int it = 0; it < 4; it++) {            // A -> LDS via DMA
      int cc = it*256 + tid;
      int r = cc >> 3, s = cc & 7;
      int kk = k0 + (((s ^ (r & 7))) << 3);
      gload16((const u16*)A + (size_t)(m0 + r)*K + kk,
              As + (size_t)(it*256 + wbase)*8);
    }
    #pragma unroll
    for (int it = 0; it < 4; it++) {            // W regs -> LDS (f16)
      int cc = it*256 + tid;
      union { uint4 u; f16 h[8]; } bbv;
      float4 x = b_st[it][0], y = b_st[it][1];
      bbv.h[0] = (f16)x.x; bbv.h[1] = (f16)x.y; bbv.h[2] = (f16)x.z; bbv.h[3] = (f16)x.w;
      bbv.h[4] = (f16)y.x; bbv.h[5] = (f16)y.y; bbv.h[6] = (f16)y.z; bbv.h[7] = (f16)y.w;
      *(uint4*)&Bs[cc*8] = bbv.u;
    }
    __syncthreads();                            // drains DMA (vmcnt) + ds
    #pragma unroll
    for (int ks = 0; ks < 2; ks++) {
      f16x8 af[4], bf[4];
      #pragma unroll
      for (int mi = 0; mi < 4; mi++) {
        int row = wm*64 + mi*16 + lr;
        int slot = (ks*4 + lg) ^ (row & 7);
        af[mi] = *(const f16x8*)&As[row*64 + slot*8];
      }
      #pragma unroll
      for (int ni = 0; ni < 4; ni++) {
        int row = wn*64 + ni*16 + lr;
        int slot = (ks*4 + lg) ^ (row & 7);
        bf[ni] = *(const f16x8*)&Bs[row*64 + slot*8];
      }
      #pragma unroll
      for (int mi = 0; mi < 4; mi++)
        #pragma unroll
        for (int ni = 0; ni < 4; ni++)
          acc[mi][ni] = __builtin_amdgcn_mfma_f32_16x16x32_f16(af[mi], bf[ni], acc[mi][ni], 0, 0, 0);
    }
  }
  __syncthreads();
  u16* Cst = lds;
  #pragma unroll
  for (int ni = 0; ni < 4; ni++) {
    int coln = wn*64 + ni*16 + lr;
    float bv = bias1[n0 + coln];
    if (bias2) bv += bias2[n0 + coln];
    #pragma unroll
    for (int mi = 0; mi < 4; mi++) {
      int rowm = wm*64 + mi*16 + lg*4;
      #pragma unroll
      for (int q = 0; q < 4; q++)
        Cst[(rowm + q)*136 + coln] = f2h(acc[mi][ni][q] + bv);
    }
  }
  __syncthreads();
  u16* Cg = (u16*)C;
  #pragma unroll
  for (int it = 0; it < 8; it++) {
    int idx = it*256 + tid;
    int r2 = idx >> 4, sg = idx & 15;
    uint4 v = *(const uint4*)&Cst[r2*136 + sg*8];
    *(uint4*)&Cg[(size_t)(m0 + r2)*N + n0 + sg*8] = v;
  }
}

__global__ __launch_bounds__(256) void k_gemm_mfma(
    const f16* __restrict__ A, const float* __restrict__ W,
    const float* __restrict__ bias1, const float* __restrict__ bias2,
    f16* __restrict__ C, int M, int N, int K) {
  __shared__ __align__(16) u16 lds[128*136];
  gemm_body(A, W, bias1, bias2, C, M, N, K, blockIdx.y << 7, blockIdx.x << 7, lds);
}

// ---------------------------------------------------------------------------
// Fused mo-GEMM (M=32768,N=256,K=256) + residual + LayerNorm(256).
// 512 thr, 8 waves (wm=wave>>2 covers 128 rows, wn=wave&3 covers 256 cols) so
// a block owns FULL rows; epilogue stages rounded-f16 C in LDS (stride 264),
// then runs the exact k_lnres reduction in-block.  Numerics identical to the
// old mo->lnres path (same f16 rounding point, same add order).
// ---------------------------------------------------------------------------
__global__ __launch_bounds__(512) void k_gemm_ln(
    const f16* __restrict__ A, const float* __restrict__ W,
    const float* __restrict__ bias, const f16* __restrict__ R,
    const float* __restrict__ g, const float* __restrict__ bb,
    f16* __restrict__ out) {
  __shared__ __align__(16) u16 lds[128*264];     // Cst; As|Bs alias the front
  u16* As = lds;                                  // [128][64] = 8192 u16
  u16* Bs = lds + 8192;                           // [256][64] = 16384 u16
  int tid = threadIdx.x;
  int wave = tid >> 6, lane = tid & 63;
  int wm = wave >> 2, wn = wave & 3;
  int lr = lane & 15, lg = lane >> 4;
  int wbase = tid & ~63;
  int m0 = (int)blockIdx.x << 7;
  f32x4 acc[4][4];
  #pragma unroll
  for (int mi = 0; mi < 4; mi++)
    #pragma unroll
    for (int ni = 0; ni < 4; ni++)
      acc[mi][ni] = (f32x4){0.0f, 0.0f, 0.0f, 0.0f};
  for (int k0 = 0; k0 < 256; k0 += 64) {
    float4 b_st[4][2];
    #pragma unroll
    for (int it = 0; it < 4; it++) {            // W -> regs (256 rows x 8 slots)
      int cc = it*512 + tid;
      int r = cc >> 3, s = cc & 7;
      int kk = k0 + (((s ^ (r & 7))) << 3);
      const float* wp = W + (size_t)r*256 + kk;
      b_st[it][0] = *(const float4*)wp;
      b_st[it][1] = *(const float4*)(wp + 4);
    }
    __syncthreads();                            // prev MFMA done with LDS
    #pragma unroll
    for (int it = 0; it < 2; it++) {            // A -> LDS via DMA (1024 chunks)
      int cc = it*512 + tid;
      int r = cc >> 3, s = cc & 7;
      int kk = k0 + (((s ^ (r & 7))) << 3);
      gload16((const u16*)A + (size_t)(m0 + r)*256 + kk,
              As + (size_t)(it*512 + wbase)*8);
    }
    #pragma unroll
    for (int it = 0; it < 4; it++) {            // W regs -> LDS (f16)
      int cc = it*512 + tid;
      union { uint4 u; f16 h[8]; } bbv;
      float4 x = b_st[it][0], y2 = b_st[it][1];
      bbv.h[0] = (f16)x.x;  bbv.h[1] = (f16)x.y;  bbv.h[2] = (f16)x.z;  bbv.h[3] = (f16)x.w;
      bbv.h[4] = (f16)y2.x; bbv.h[5] = (f16)y2.y; bbv.h[6] = (f16)y2.z; bbv.h[7] = (f16)y2.w;
      *(uint4*)&Bs[cc*8] = bbv.u;
    }
    __syncthreads();                            // drains DMA (vmcnt) + ds
    #pragma unroll
    for (int ks = 0; ks < 2; ks++) {
      f16x8 af[4], bf[4];
      #pragma unroll
      for (int mi = 0; mi < 4; mi++) {
        int row = wm*64 + mi*16 + lr;           // 0..127
        int slot = (ks*4 + lg) ^ (row & 7);
        af[mi] = *(const f16x8*)&As[row*64 + slot*8];
      }
      #pragma unroll
      for (int ni = 0; ni < 4; ni++) {
        int row = wn*64 + ni*16 + lr;           // 0..255
        int slot = (ks*4 + lg) ^ (row & 7);
        bf[ni] = *(const f16x8*)&Bs[row*64 + slot*8];
      }
      #pragma unroll
      for (int mi = 0; mi < 4; mi++)
        #pragma unroll
        for (int ni = 0; ni < 4; ni++)
          acc[mi][ni] = __builtin_amdgcn_mfma_f32_16x16x32_f16(af[mi], bf[ni], acc[mi][ni], 0, 0, 0);
    }
  }
  __syncthreads();
  // stage rounded-f16 C (matches old global mo rounding) into [128][264]
  #pragma unroll
  for (int ni = 0; ni < 4; ni++) {
    int coln = wn*64 + ni*16 + lr;
    float bv = bias[coln];
    #pragma unroll
    for (int mi = 0; mi < 4; mi++) {
      int rowm = wm*64 + mi*16 + lg*4;
      #pragma unroll
      for (int q = 0; q < 4; q++)
        lds[(rowm + q)*264 + coln] = f2h(acc[mi][ni][q] + bv);
    }
  }
  __syncthreads();
  // residual + LayerNorm(256), exact k_lnres body (row-per-64-lanes)
  #pragma unroll
  for (int it = 0; it < 16; it++) {
    int row = it*8 + wave;
    const u16* crow = &lds[row*264 + lane*4];
    const f16* rr = R + ((size_t)(m0 + row))*256 + lane*4;
    float v0 = h2fu(crow[0]) + (float)rr[0];
    float v1 = h2fu(crow[1]) + (float)rr[1];
    float v2 = h2fu(crow[2]) + (float)rr[2];
    float v3 = h2fu(crow[3]) + (float)rr[3];
    float s = v0 + v1 + v2 + v3;
    float q = v0*v0 + v1*v1 + v2*v2 + v3*v3;
    #pragma unroll
    for (int off = 32; off; off >>= 1) { s += __shfl_xor(s, off); q += __shfl_xor(q, off); }
    float mean = s*(1.0f/256.0f);
    float var  = q*(1.0f/256.0f) - mean*mean;
    float rstd = rsqrtf(var + 1e-5f);
    int d0 = lane*4;
    f16* op = out + ((size_t)(m0 + row))*256 + d0;
    op[0] = (f16)((v0 - mean)*rstd*g[d0+0] + bb[d0+0]);
    op[1] = (f16)((v1 - mean)*rstd*g[d0+1] + bb[d0+1]);
    op[2] = (f16)((v2 - mean)*rstd*g[d0+2] + bb[d0+2]);
    op[3] = (f16)((v3 - mean)*rstd*g[d0+3] + bb[d0+3]);
  }
}

// ---------------------------------------------------------------------------
// Dual A-sharing GEMM, M_TILE=256, XCD remap, DMA A-staging.  (validated r20)
// ---------------------------------------------------------------------------
__global__ __launch_bounds__(512) void k_gemm_dual2(
    const f16* __restrict__ A,
    const float* __restrict__ Wf, const float* __restrict__ Wb,
    const float* __restrict__ b1f, const float* __restrict__ b2f,
    const float* __restrict__ b1b, const float* __restrict__ b2b,
    f16* __restrict__ Cf, f16* __restrict__ Cb, int M, int N, int K) {
  __shared__ __align__(16) u16 lds[256*64 + 128*64];   // As | Bs ; Cst reuses
  u16* As = lds;
  u16* Bs = lds + 256*64;
  int tid = threadIdx.x;
  int wave = tid >> 6, lane = tid & 63;
  int wm = wave >> 1, wn = wave & 1;
  int lr = lane & 15, lg = lane >> 4;
  int stripes_per_xcd = M >> 11;
  int xcd = (int)blockIdx.x, y = (int)blockIdx.y;
  int sel = y & 7;
  int mstripe = xcd*stripes_per_xcd + (y >> 3);
  int which = sel >> 2;
  int n0 = (sel & 3) << 7;
  int m0 = mstripe << 8;
  const float* W  = which ? Wb  : Wf;
  const float* b1 = which ? b1b : b1f;
  const float* b2 = which ? b2b : b2f;
  f16* C = which ? Cb : Cf;
  f32x4 acc[4][4];
  #pragma unroll
  for (int mi = 0; mi < 4; mi++)
    #pragma unroll
    for (int ni = 0; ni < 4; ni++)
      acc[mi][ni] = (f32x4){0.0f, 0.0f, 0.0f, 0.0f};
  int wbase = tid & ~63;
  for (int k0 = 0; k0 < K; k0 += 64) {
    float4 b_st[2][2];
    #pragma unroll
    for (int it = 0; it < 2; it++) {
      int cc = it*512 + tid;
      int r = cc >> 3, s = cc & 7;
      int kk = k0 + (((s ^ (r & 7))) << 3);
      const float* wp = W + (size_t)(n0 + r)*K + kk;
      b_st[it][0] = *(const float4*)wp;
      b_st[it][1] = *(const float4*)(wp + 4);
    }
    __syncthreads();
    #pragma unroll
    for (int it = 0; it < 4; it++) {
      int cc = it*512 + tid;
      int r = cc >> 3, s = cc & 7;
      int kk = k0 + (((s ^ (r & 7))) << 3);
      gload16((const u16*)A + (size_t)(m0 + r)*K + kk,
              As + (size_t)(it*512 + wbase)*8);
    }
    #pragma unroll
    for (int it = 0; it < 2; it++) {
      int cc = it*512 + tid;
      union { uint4 u; f16 h[8]; } bbv;
      float4 x = b_st[it][0], y2 = b_st[it][1];
      bbv.h[0] = (f16)x.x;  bbv.h[1] = (f16)x.y;  bbv.h[2] = (f16)x.z;  bbv.h[3] = (f16)x.w;
      bbv.h[4] = (f16)y2.x; bbv.h[5] = (f16)y2.y; bbv.h[6] = (f16)y2.z; bbv.h[7] = (f16)y2.w;
      *(uint4*)&Bs[cc*8] = bbv.u;
    }
    __syncthreads();
    #pragma unroll
    for (int ks = 0; ks < 2; ks++) {
      f16x8 af[4], bf[4];
      #pragma unroll
      for (int mi = 0; mi < 4; mi++) {
        int row = wm*64 + mi*16 + lr;
        int slot = (ks*4 + lg) ^ (row & 7);
        af[mi] = *(const f16x8*)&As[row*64 + slot*8];
      }
      #pragma unroll
      for (int ni = 0; ni < 4; ni++) {
        int row = wn*64 + ni*16 + lr;
        int slot = (ks*4 + lg) ^ (row & 7);
        bf[ni] = *(const f16x8*)&Bs[row*64 + slot*8];
      }
      #pragma unroll
      for (int mi = 0; mi < 4; mi++)
        #pragma unroll
        for (int ni = 0; ni < 4; ni++)
          acc[mi][ni] = __builtin_amdgcn_mfma_f32_16x16x32_f16(af[mi], bf[ni], acc[mi][ni], 0, 0, 0);
    }
  }
  u16* Cst = lds;
  u16* Cg = (u16*)C;
  #pragma unroll
  for (int half = 0; half < 2; half++) {
    __syncthreads();
    if (wm == half*2 || wm == half*2 + 1) {
      int lwm = wm - half*2;
      #pragma unroll
      for (int ni = 0; ni < 4; ni++) {
        int coln = wn*64 + ni*16 + lr;
        float bv = b1[n0 + coln];
        if (b2) bv += b2[n0 + coln];
        #pragma unroll
        for (int mi = 0; mi < 4; mi++) {
          int rowm = lwm*64 + mi*16 + lg*4;
          #pragma unroll
          for (int q = 0; q < 4; q++)
            Cst[(rowm + q)*136 + coln] = f2h(acc[mi][ni][q] + bv);
        }
      }
    }
    __syncthreads();
    #pragma unroll
    for (int it = 0; it < 4; it++) {
      int idx = it*512 + tid;
      int r2 = idx >> 4, sg = idx & 15;
      uint4 v = *(const uint4*)&Cst[r2*136 + sg*8];
      *(uint4*)&Cg[(size_t)(m0 + half*128 + r2)*N + n0 + sg*8] = v;
    }
  }
}

// ---------------------------------------------------------------------------
// LSTM recurrence via MFMA.  4 seqs/block.  (validated r14)
// ---------------------------------------------------------------------------
__global__ __launch_bounds__(512) void k_lstm_mfma(
    const f16* __restrict__ pre_f, const f16* __restrict__ pre_b,
    const float* __restrict__ whh_f, const float* __restrict__ whh_b,
    f16* __restrict__ hout) {
  __shared__ __align__(16) u16 hlh[16*136];
  __shared__ float gl[4*516];
  int tid = threadIdx.x;
  int dir = blockIdx.x & 1;
  int b0  = (blockIdx.x >> 1) << 2;
  const f16* pre = dir ? pre_b : pre_f;
  const float* whh = dir ? whh_b : whh_f;
  int wave = tid >> 6, lane = tid & 63;
  int lr = lane & 15, lg = lane >> 4;
  f16x8 bw[4][4];
  #pragma unroll
  for (int nt = 0; nt < 4; nt++) {
    int j = (wave*4 + nt)*16 + lr;
    #pragma unroll
    for (int kb = 0; kb < 4; kb++) {
      const float* wp = whh + (size_t)j*128 + kb*32 + lg*8;
      f16x8 v;
      #pragma unroll
      for (int e = 0; e < 8; e++) v[e] = (f16)wp[e];
      bw[nt][kb] = v;
    }
  }
  for (int i = tid; i < 16*136; i += 512) hlh[i] = 0;
  int s_a = tid >> 7;
  int u   = tid & 127;
  size_t prow = (size_t)(b0 + s_a)*128;
  const u16* preu = (const u16*)pre;
  int t0 = dir ? 127 : 0;
  u16 pi = preu[(prow + t0)*512 + u];
  u16 pf = preu[(prow + t0)*512 + 128 + u];
  u16 pg = preu[(prow + t0)*512 + 256 + u];
  u16 po = preu[(prow + t0)*512 + 384 + u];
  float c = 0.0f;
  u16* houtu = (u16*)hout;
  __syncthreads();
  for (int s = 0; s < 128; s++) {
    int t = dir ? (127 - s) : s;
    f16x8 af[4];
    #pragma unroll
    for (int kb = 0; kb < 4; kb++)
      af[kb] = *(const f16x8*)&hlh[lr*136 + kb*32 + lg*8];
    #pragma unroll
    for (int nt = 0; nt < 4; nt++) {
      f32x4 acc = {0.0f, 0.0f, 0.0f, 0.0f};
      #pragma unroll
      for (int kb = 0; kb < 4; kb++)
        acc = __builtin_amdgcn_mfma_f32_16x16x32_f16(af[kb], bw[nt][kb], acc, 0, 0, 0);
      if (lg == 0) {
        int jc = (wave*4 + nt)*16 + lr;
        #pragma unroll
        for (int q = 0; q < 4; q++)
          gl[q*516 + jc] = acc[q];
      }
    }
    __syncthreads();
    float gi = gl[s_a*516 + u];
    float gf = gl[s_a*516 + 128 + u];
    float gg = gl[s_a*516 + 256 + u];
    float go = gl[s_a*516 + 384 + u];
    u16 ni = pi, nf = pf, ng = pg, no = po;
    if (s < 127) {
      int tn = dir ? (126 - s) : (s + 1);
      pi = preu[(prow + tn)*512 + u];
      pf = preu[(prow + tn)*512 + 128 + u];
      pg = preu[(prow + tn)*512 + 256 + u];
      po = preu[(prow + tn)*512 + 384 + u];
    }
    float iv = gi + h2fu(ni), fv = gf + h2fu(nf);
    float gv = gg + h2fu(ng), ov = go + h2fu(no);
    c = sigmf(fv)*c + sigmf(iv)*tanhfast(gv);
    float hv = sigmf(ov)*tanhfast(c);
    u16 hw = f2h(hv);
    hlh[s_a*136 + u] = hw;
    houtu[(prow + t)*256 + (dir << 7) + u] = hw;
    __syncthreads();
  }
}

// ---------------------------------------------------------------------------
// MHA via MFMA.  (unchanged — validated round 10)
// ---------------------------------------------------------------------------
__global__ __launch_bounds__(256) void k_mha_mfma(const f16* __restrict__ qkv, f16* __restrict__ o) {
  __shared__ __align__(16) u16 smemA[128*144];
  __shared__ __align__(16) u16 vt[64*136];
  int b = blockIdx.x, h = blockIdx.y, tid = threadIdx.x;
  int wave = tid >> 6, lane = tid & 63;
  int lr = lane & 15, lg = lane >> 4;
  u16* qs = smemA;
  u16* ks = smemA + 128*72;
  const u16* base = (const u16*)(qkv + (size_t)b*98304 + h*64);
  const u32* base32 = (const u32*)base;
  for (int i = tid; i < 4096; i += 256) {
    int t = i >> 5, d2 = i & 31;
    *(u32*)&qs[t*72 + (d2 << 1)] = base32[t*384 + d2];
    *(u32*)&ks[t*72 + (d2 << 1)] = base32[t*384 + 128 + d2];
  }
  for (int i = tid; i < 8192; i += 256) {
    int t = i >> 6, d = i & 63;
    vt[d*136 + t] = base[t*768 + 512 + d];
  }
  __syncthreads();
  f32x4 sacc[2][8];
  {
    f16x8 aq[2][2];
    #pragma unroll
    for (int mi = 0; mi < 2; mi++) {
      int mt = wave*2 + mi;
      #pragma unroll
      for (int kb = 0; kb < 2; kb++)
        aq[mi][kb] = *(const f16x8*)&qs[(mt*16 + lr)*72 + kb*32 + lg*8];
    }
    #pragma unroll
    for (int mi = 0; mi < 2; mi++)
      #pragma unroll
      for (int nt = 0; nt < 8; nt++) {
        f32x4 acc = {0.0f, 0.0f, 0.0f, 0.0f};
        #pragma unroll
        for (int kb = 0; kb < 2; kb++) {
          f16x8 bf = *(const f16x8*)&ks[(nt*16 + lr)*72 + kb*32 + lg*8];
          acc = __builtin_amdgcn_mfma_f32_16x16x32_f16(aq[mi][kb], bf, acc, 0, 0, 0);
        }
        sacc[mi][nt] = acc;
      }
  }
  __syncthreads();
  u16* ps = smemA;
  #pragma unroll
  for (int mi = 0; mi < 2; mi++) {
    int rb = (wave*2 + mi)*16 + lg*4;
    #pragma unroll
    for (int q = 0; q < 4; q++) {
      float pv[8]; float mx = -1e30f;
      #pragma unroll
      for (int nt = 0; nt < 8; nt++) { float v = sacc[mi][nt][q]*0.125f; pv[nt] = v; mx = fmaxf(mx, v); }
      mx = fmaxf(mx, __shfl_xor(mx, 1));
      mx = fmaxf(mx, __shfl_xor(mx, 2));
      mx = fmaxf(mx, __shfl_xor(mx, 4));
      mx = fmaxf(mx, __shfl_xor(mx, 8));
      float sum = 0.0f;
      #pragma unroll
      for (int nt = 0; nt < 8; nt++) { float e = __expf(pv[nt] - mx); pv[nt] = e; sum += e; }
      sum += __shfl_xor(sum, 1);
      sum += __shfl_xor(sum, 2);
      sum += __shfl_xor(sum, 4);
      sum += __shfl_xor(sum, 8);
      float inv = 1.0f/sum;
      #pragma unroll
      for (int nt = 0; nt < 8; nt++)
        ps[(rb + q)*136 + nt*16 + lr] = f2h(pv[nt]*inv);
    }
  }
  __syncthreads();
  f32x4 oacc[2][4];
  {
    f16x8 ap[2][4];
    #pragma unroll
    for (int mi = 0; mi < 2; mi++) {
      int mt = wave*2 + mi;
      #pragma unroll
      for (int kb = 0; kb < 4; kb++)
        ap[mi][kb] = *(const f16x8*)&ps[(mt*16 + lr)*136 + kb*32 + lg*8];
    }
    #pragma unroll
    for (int mi = 0; mi < 2; mi++)
      #pragma unroll
      for (int nt = 0; nt < 4; nt++) {
        f32x4 acc = {0.0f, 0.0f, 0.0f, 0.0f};
        #pragma unroll
        for (int kb = 0; kb < 4; kb++) {
          f16x8 bf = *(const f16x8*)&vt[(nt*16 + lr)*136 + kb*32 + lg*8];
          acc = __builtin_amdgcn_mfma_f32_16x16x32_f16(ap[mi][kb], bf, acc, 0, 0, 0);
        }
        oacc[mi][nt] = acc;
      }
  }
  u16* og = (u16*)o;
  #pragma unroll
  for (int mi = 0; mi < 2; mi++) {
    int rb = (wave*2 + mi)*16 + lg*4;
    #pragma unroll
    for (int nt = 0; nt < 4; nt++) {
      int col = h*64 + nt*16 + lr;
      #pragma unroll
      for (int q = 0; q < 4; q++)
        og[((size_t)b*128 + rb + q)*256 + col] = f2h(oacc[mi][nt][q]);
    }
  }
}

// ---------------------------------------------------------------------------
// mean/max pool over T, LayerNorm(512), cls1+ReLU, cls2.  (unchanged)
// ---------------------------------------------------------------------------
__global__ __launch_bounds__(512) void k_pool_cls(
    const f16* __restrict__ att, const float* __restrict__ png, const float* __restrict__ pnb,
    const float* __restrict__ w1, const float* __restrict__ b1,
    const float* __restrict__ w2, const float* __restrict__ b2, float* __restrict__ out) {
  __shared__ float pl[512];
  __shared__ float redS[8], redQ[8];
  __shared__ float mrv[2];
  __shared__ float hl[128];
  int b = blockIdx.x, tid = threadIdx.x;
  if (tid < 256) {
    const f16* ar = att + (size_t)b*32768 + tid;
    float s = 0.0f, mx = -1e30f;
    for (int t = 0; t < 128; t++) { float v = (float)ar[t*256]; s += v; mx = fmaxf(mx, v); }
    pl[tid] = s*(1.0f/128.0f);
    pl[256 + tid] = mx;
  }
  __syncthreads();
  float v = pl[tid];
  float s = v, q = v*v;
  #pragma unroll
  for (int off = 32; off; off >>= 1) { s += __shfl_xor(s, off); q += __shfl_xor(q, off); }
  if ((tid & 63) == 0) { redS[tid >> 6] = s; redQ[tid >> 6] = q; }
  __syncthreads();
  if (tid == 0) {
    float S = 0.0f, Q = 0.0f;
    #pragma unroll
    for (int w = 0; w < 8; w++) { S += redS[w]; Q += redQ[w]; }
    float mean = S*(1.0f/512.0f);
    float var  = Q*(1.0f/512.0f) - mean*mean;
    mrv[0] = mean; mrv[1] = rsqrtf(var + 1e-5f);
  }
  __syncthreads();
  pl[tid] = (v - mrv[0])*mrv[1]*png[tid] + pnb[tid];
  __syncthreads();
  if (tid < 128) {
    float acc = b1[tid];
    const float* wrp = w1 + (size_t)tid*512;
    for (int d = 0; d < 512; d++) acc += pl[d]*wrp[d];
    hl[tid] = fmaxf(acc, 0.0f)*w2[tid];
  }
  __syncthreads();
  if (tid < 64) {
    float rsum = hl[tid] + hl[tid + 64];
    #pragma unroll
    for (int off = 32; off; off >>= 1) rsum += __shfl_xor(rsum, off);
    if (tid == 0) out[b] = rsum + b2[0];
  }
}

// ---------------------------------------------------------------------------
extern "C" void kernel_launch(void* const* d_in, const int* in_sizes, int n_in,
                              void* d_out, int out_size, void* d_ws, size_t ws_size,
                              hipStream_t stream) {
  (void)in_sizes; (void)n_in; (void)out_size;
  if (ws_size < (size_t)192*1024*1024) return;
  const float* IN[47];
  for (int i = 0; i < 47; i++) IN[i] = (const float*)d_in[i];
  char* W8 = (char*)d_ws;
  f16* feat     = (f16*)(W8 + ((size_t)0  << 20));  // [0,64)
  f16* g        = (f16*)(W8 + ((size_t)64 << 20));  // [64,192)
  f16* pre_f    = (f16*)(W8 + ((size_t)0  << 20));  // [0,32)
  f16* pre_b    = (f16*)(W8 + ((size_t)32 << 20));  // [32,64)
  f16* h1       = (f16*)(W8 + ((size_t)64 << 20));  // [64,80)
  f16* lstm_out = (f16*)(W8 + ((size_t)80 << 20));  // [80,96)
  f16* qkv      = (f16*)(W8 + ((size_t)96 << 20));  // [96,144)
  f16* o_flat   = (f16*)(W8 + ((size_t)0  << 20));  // [0,16)
  f16* att      = (f16*)(W8 + ((size_t)32 << 20));  // [32,48)
  // wt2p: feat region — dead after gat<64>, overwritten by pre_f later (r27).
  u16* wt2p     = (u16*)W8;

  k_conv<<<4096, 256, 0, stream>>>(IN[0], IN[1], IN[2], IN[3], IN[4],
                                   IN[5], IN[6], IN[7], IN[8], feat);
  k_gat_mfma<64, false><<<4096, 512, 0, stream>>>(IN[9], nullptr, feat,
                                                  IN[10], IN[11], IN[12], IN[13], g);
  k_prep_gat2<<<68, 256, 0, stream>>>(IN[14], wt2p);
  k_gat_mfma<128, true><<<4096, 512, 0, stream>>>(nullptr, (const f16*)wt2p, g,
                                                  IN[15], IN[16], IN[17], IN[18], g);
  k_gemm_dual2<<<dim3(8, 128), 512, 0, stream>>>(g, IN[19], IN[23], IN[21], IN[22],
                                                 IN[25], IN[26], pre_f, pre_b, 32768, 512, 2048);
  k_lstm_mfma<<<128, 512, 0, stream>>>(pre_f, pre_b, IN[20], IN[24], h1);
  k_gemm_dual2<<<dim3(8, 128), 512, 0, stream>>>(h1, IN[27], IN[31], IN[29], IN[30],
                                                 IN[33], IN[34], pre_f, pre_b, 32768, 512, 256);
  k_lstm_mfma<<<128, 512, 0, stream>>>(pre_f, pre_b, IN[28], IN[32], lstm_out);
  k_gemm_mfma<<<dim3(6, 256), 256, 0, stream>>>(lstm_out, IN[35], IN[36], nullptr, qkv, 32768, 768, 256);
  k_mha_mfma<<<dim3(256, 4), 256, 0, stream>>>(qkv, o_flat);
  k_gemm_ln<<<256, 512, 0, stream>>>(o_flat, IN[37], IN[38], lstm_out, IN[39], IN[40], att);
  k_pool_cls<<<256, 512, 0, stream>>>(att, IN[41], IN[42], IN[43], IN[44], IN[45], IN[46],
                                      (float*)d_out);
}